// Round 7
// baseline (209.605 us; speedup 1.0000x reference)
//
#include <hip/hip_runtime.h>

// SNN direction decoder — fused MFMA GEMM + LIF scan + FC2.
// B=256, T=100, I=512, H=1024, C=8.
// R10 (resubmit; prior bench was an infra failure — container acquire
// flake, same as R3/R4 — no kernel signal): R9's panelized staging +
// R6's 64x128 wave tile (the LDS-read/MFMA ratio lever), now safe because:
//  - R6's real problem was staging scatter (fixed by panels, proven R8->R9);
//  - R7's real problem was (256,3) forcing a 601MB scratch spill; (256,2)
//    holds 184 unified regs (128 acc AGPR + ~56 VGPR) = 2 waves/SIMD.
// Arithmetic: 64x64 tiles read 8 b128 frags per 12 MFMA -> LDS ~60us/CU >
// MFMA floor 41us. 64x128 reads 12 per 24 -> LDS ~36us/CU < 41us floor.
// SQ_LDS_BANK_CONFLICT = 8 x gload_lds count is an LDS-write-burst
// accounting artifact (invariant across R8->R9 layout change) — ignored.
// Splitter: block-per-panel, waves read full 2KB rows (coalesced); 32B
// cell writes L2-merge within the block.
// fp32 GEMM emulated as 3-term f16 (xh*wh + xh*wl + xl*wh), inputs
// pre-scaled 2^6, un-scaled 2^-12 at epilogue.

#define B_   256
#define T_   100
#define I_   512
#define H_   1024
#define C_   8
#define M_   (B_ * T_)        // 25600
#define SC   64.0f            // 2^6 pre-scale
#define ISC  (1.0f / 4096.0f) // 2^-12 epilogue un-scale

// Panel layout (halfs): cell = 32 rows x 16 halfs = 512 (1024 B contiguous);
// s-half = 32 chunks x cell = 16384; panel = hi|lo = 32768 (64 KB).
#define CELL_  512
#define SHALF_ 16384
#define PANEL_ 32768

typedef _Float16 half8 __attribute__((ext_vector_type(8)));
typedef float floatx16 __attribute__((ext_vector_type(16)));

__device__ __forceinline__ void ld_g2l(const _Float16* g, _Float16* l) {
    // async global->LDS, 16B/lane; LDS dest = wave-uniform base + lane*16
    __builtin_amdgcn_global_load_lds(
        (const __attribute__((address_space(1))) void*)g,
        (__attribute__((address_space(3))) void*)l, 16, 0, 0);
}

// Splitter: block p < 800 handles A panel p (x rows p*32+[0,32)); blocks
// 800..831 handle W1 panel p-800. 8 iters: wave w reads row j*4+w in full
// (64 lanes x 32B = 2KB, perfectly coalesced), splits, writes hi/lo 16B
// pieces into the row's slots of all 32 cells. Blocks 0..7 init logits.
__global__ void __launch_bounds__(256)
split_all(const float* __restrict__ x, const float* __restrict__ W1,
          const float* __restrict__ b2, _Float16* __restrict__ Asp,
          float* __restrict__ out) {
    const int tid = threadIdx.x;
    const int lane = tid & 63;
    const int w = tid >> 6;
    const int p = blockIdx.x;
    int g = p * 256 + tid;
    if (g < B_ * C_) out[g] = 100.0f * b2[g & (C_ - 1)];

    const bool isA = (p < 800);
    const int pl = isA ? p : (p - 800);
    const float* srcm = isA ? x : W1;
    _Float16* dstp = Asp + (size_t)(isA ? pl : (800 + pl)) * PANEL_;
#pragma unroll 2
    for (int j = 0; j < 8; ++j) {
        const int rl = j * 4 + w;                 // row 0..31 within panel
        const int r  = pl * 32 + rl;              // source matrix row
        const float* src = srcm + (size_t)r * I_ + lane * 8;
        float4 v0 = *(const float4*)(src);
        float4 v1 = *(const float4*)(src + 4);
        float vv[8] = {v0.x, v0.y, v0.z, v0.w, v1.x, v1.y, v1.z, v1.w};
        half8 hi, lo;
#pragma unroll
        for (int q = 0; q < 8; ++q) {
            float s = vv[q] * SC;
            _Float16 h = (_Float16)s;
            hi[q] = h;
            lo[q] = (_Float16)(s - (float)h);
        }
        // dest: cell = lane>>1 (=col/16), within-cell ofs rl*16 + (lane&1)*8
        _Float16* d = dstp + (lane >> 1) * CELL_ + rl * 16 + (lane & 1) * 8;
        *(half8*)(d) = hi;
        *(half8*)(d + SHALF_) = lo;
    }
}

#define MFMA32(A, Bv, Cacc) \
    Cacc = __builtin_amdgcn_mfma_f32_32x32x16_f16(A, Bv, Cacc, 0, 0, 0)

// One chunk = 16 k-halfs of {Ah,Al} (128 t-rows) and {Bh,Bl} (256 h-rows).
// LDS buffer (halfs): Ah[128*16]=2048 @0 | Al @2048 | Bh[256*16]=4096 @4096
// | Bl @8192. Buffer stride 12288 halfs (24 KB). Wave w stages A cell w
// (rows 32w..32w+32) and B cells 2w,2w+1 (rows 64w..64w+64), hi+lo:
// 6 gload_lds/wave/chunk, each 1024B contiguous src AND dest.
#define STAGE(dd, cc) do {                                           \
    _Float16* lb = &sm.buf[0][0] + (dd) * 12288;                     \
    ld_g2l(gah  + (cc) * CELL_, lb + w * 512);                       \
    ld_g2l(gal  + (cc) * CELL_, lb + 2048 + w * 512);                \
    ld_g2l(gbh0 + (cc) * CELL_, lb + 4096 + w * 1024);               \
    ld_g2l(gbh1 + (cc) * CELL_, lb + 4096 + w * 1024 + 512);         \
    ld_g2l(gbl0 + (cc) * CELL_, lb + 8192 + w * 1024);               \
    ld_g2l(gbl1 + (cc) * CELL_, lb + 8192 + w * 1024 + 512);         \
} while (0)

// (ra/rb + f*512 safe: f*512 is a multiple of 512 halfs, above the XOR bits)
#define COMPUTE(dd) do {                                             \
    const _Float16* bb = &sm.buf[0][0] + (dd) * 12288;               \
    half8 ah[2], al[2], bh[4], bl[4];                                \
    _Pragma("unroll")                                                \
    for (int f = 0; f < 2; ++f) {                                    \
        ah[f] = *(const half8*)(bb + ra + f * 512);                  \
        al[f] = *(const half8*)(bb + 2048 + ra + f * 512);           \
    }                                                                \
    _Pragma("unroll")                                                \
    for (int f = 0; f < 4; ++f) {                                    \
        bh[f] = *(const half8*)(bb + 4096 + rb + f * 512);           \
        bl[f] = *(const half8*)(bb + 8192 + rb + f * 512);           \
    }                                                                \
    _Pragma("unroll")                                                \
    for (int fm = 0; fm < 2; ++fm) {                                 \
        _Pragma("unroll")                                            \
        for (int fn = 0; fn < 4; ++fn) {                             \
            MFMA32(ah[fm], bh[fn], acc[fm][fn]);                     \
            MFMA32(ah[fm], bl[fn], acc[fm][fn]);                     \
            MFMA32(al[fm], bh[fn], acc[fm][fn]);                     \
        }                                                            \
    }                                                                \
} while (0)

// Fused: C-tile[t 0..127][256 h], LIF scan + FC2. One batch per block, 4
// h-tiles of 256. XCD-swizzled: xcd=blk&7 owns batches [32*xcd, 32*xcd+32);
// consecutive jj = same batch's 4 h-tiles (A L2 reuse). A rows 100..127
// overread into following panels (masked in scan).
__global__ void __launch_bounds__(256, 2)
snn_mfma(const _Float16* __restrict__ Asp, const _Float16* __restrict__ Wsp,
         const float* __restrict__ b1, const float* __restrict__ W2,
         float* __restrict__ logits) {
    __shared__ union {
        __align__(16) _Float16 buf[2][12288];  // double-buffered chunk (48 KB)
        float Cs[32 * 256];                    // epilogue staging (32 KB)
    } sm;
    const int tid = threadIdx.x;
    const int lane = tid & 63;
    const int w = tid >> 6;

    const int xcd = blockIdx.x & 7;
    const int jj = blockIdx.x >> 3;        // 0..127 per-XCD sequence
    const int b  = xcd * 32 + (jj >> 2);   // batch 0..255
    const int n0 = (jj & 3) * 256;         // h tile offset

    const int wm = (w >> 1) * 64;   // wave's 64x128 sub-tile
    const int wn = (w & 1) * 128;
    const int l31 = lane & 31;
    const int q2 = lane >> 5;

    // ---- staging pointers (write side of the swizzle) ----
    // lane l's gload_lds writes LDS halfs [base + l*8); it carries logical
    // lane lp = l ^ ((l>>3)&7) (involution): row lp>>1, 8-half group lp&1.
    const int lp = lane ^ ((lane >> 3) & 7);
    const int ra_row = b * T_ + w * 32 + (lp >> 1);        // A matrix row
    const int rb_row = n0 + w * 64 + (lp >> 1);            // B cell0 row
    const _Float16* gah = Asp + (size_t)(ra_row >> 5) * PANEL_
                              + (ra_row & 31) * 16 + (lp & 1) * 8;
    const _Float16* gal = gah + SHALF_;
    const _Float16* gbh0 = Wsp + (size_t)(rb_row >> 5) * PANEL_
                               + (rb_row & 31) * 16 + (lp & 1) * 8;
    const _Float16* gbh1 = gbh0 + PANEL_;      // +32 rows = next panel
    const _Float16* gbl0 = gbh0 + SHALF_;
    const _Float16* gbl1 = gbh1 + SHALF_;

    // ---- fragment LDS offsets (read side of the swizzle), half units ----
    // raw = row*16 + q2*8; XOR half-bits 3..5 with row bits 2..4. All added
    // offsets (f*512, region bases, dd*12288) are multiples of 512 halfs ->
    // commute with the XOR. Per 16-lane phase each 16B bank-quad gets
    // exactly 2 lanes (2-way = free, m136).
    const int swz = ((l31 >> 2) & 7) << 3;
    const int ra = ((wm + l31) * 16 + q2 * 8) ^ swz;
    const int rb = ((wn + l31) * 16 + q2 * 8) ^ swz;

    floatx16 acc[2][4];
#pragma unroll
    for (int i = 0; i < 2; ++i)
#pragma unroll
        for (int j = 0; j < 4; ++j)
#pragma unroll
            for (int e = 0; e < 16; ++e) acc[i][j][e] = 0.f;

    STAGE(0, 0);
#pragma unroll 2
    for (int c = 0; c < 31; ++c) {
        const int d = c & 1;
        STAGE(d ^ 1, c + 1);
        asm volatile("s_waitcnt vmcnt(6)" ::: "memory");
        __builtin_amdgcn_s_barrier();
        COMPUTE(d);
        __builtin_amdgcn_s_barrier();
        asm volatile("" ::: "memory");
    }
    asm volatile("s_waitcnt vmcnt(0)" ::: "memory");
    __builtin_amdgcn_s_barrier();
    COMPUTE(1);
    __syncthreads();   // full fence: all ds reads/loads done before Cs overwrite

    // ---- epilogue: acc -> LDS (four 32-row phases) -> LIF scan + FC2 ----
    float b1c[4];
#pragma unroll
    for (int fn = 0; fn < 4; ++fn) b1c[fn] = b1[n0 + wn + fn * 32 + l31];

    float mem = 0.f, ss = 0.f;

    // phase p covers tile rows [32p, 32p+32): written by waves 0,1 (wm=0)
    // for p<2 with fm=p, by waves 2,3 for p>=2 with fm=p-2.
#pragma unroll
    for (int p = 0; p < 4; ++p) {
        const int fm = p & 1;
        if ((w >> 1) == (p >> 1)) {
#pragma unroll
            for (int r = 0; r < 16; ++r) {
                const int row = (r & 3) + 8 * (r >> 2) + 4 * q2;  // 0..31
                float* dst = &sm.Cs[row * 256 + wn + l31];
#pragma unroll
                for (int fn = 0; fn < 4; ++fn)
                    dst[fn * 32] = acc[fm][fn][r] * ISC + b1c[fn];
            }
        }
        __syncthreads();
        const int nt = (p == 3) ? 4 : 32;   // t 96..99 only in last phase
#pragma unroll 8
        for (int t = 0; t < nt; ++t) {
            float cv = sm.Cs[t * 256 + tid];
            float reset = (mem > 1.0f) ? 1.0f : 0.0f;
            mem = 0.9f * mem + cv - reset;
            ss += (mem > 1.0f) ? 1.0f : 0.0f;
        }
        __syncthreads();
    }

    // ---- FC2: logits[b][c] += sum_h ss * W2[c][h] ----
#pragma unroll
    for (int cc = 0; cc < C_; ++cc) {
        float v = ss * W2[cc * H_ + n0 + tid];
#pragma unroll
        for (int off = 32; off; off >>= 1) v += __shfl_down(v, off, 64);
        if (lane == 0) atomicAdd(&logits[b * C_ + cc], v);
    }
}

extern "C" void kernel_launch(void* const* d_in, const int* in_sizes, int n_in,
                              void* d_out, int out_size, void* d_ws, size_t ws_size,
                              hipStream_t stream) {
    const float* x  = (const float*)d_in[0];
    const float* W1 = (const float*)d_in[1];
    const float* b1 = (const float*)d_in[2];
    const float* W2 = (const float*)d_in[3];
    const float* b2 = (const float*)d_in[4];
    float* out = (float*)d_out;

    // workspace: Asp = 800 panels (52.4 MB), Wsp = 32 panels (2 MB) directly
    // after (fused kernel's tail rows overread into Wsp panels by design).
    char* ws = (char*)d_ws;
    _Float16* Asp = (_Float16*)ws;
    _Float16* Wsp = Asp + (size_t)800 * PANEL_;

    hipLaunchKernelGGL(split_all, dim3(832), dim3(256), 0, stream,
                       x, W1, b2, Asp, out);
    hipLaunchKernelGGL(snn_mfma, dim3(B_ * 4), dim3(256), 0, stream,
                       Asp, Wsp, b1, W2, out);
}

// Round 8
// 204.347 us; speedup vs baseline: 1.0257x; 1.0257x over previous
//
#include <hip/hip_runtime.h>

// SNN direction decoder — fused MFMA GEMM + LIF scan + FC2.
// B=256, T=100, I=512, H=1024, C=8.
// R11: schedule rewrite (geometry = R10). Evidence: R9 (2x LDS traffic,
// 2.7 blk/CU) and R10 (1x, 2 blk/CU) BOTH run 108us @ MfmaUtil 45.5% ->
// limiter is the 2-phase-per-chunk schedule (barrier convoy), not traffic
// or occupancy. Fix per T3/T4/T5 regime-gate evidence:
//  - 3-buffer depth-2 pipeline: stage chunk c+2 during chunk c (3+3 loads
//    across the two phases); vmcnt(6) at chunk boundary waits only c+1's
//    loads (never drains); each load has ~2 chunk-times to land.
//  - 2 phases per chunk (fn 0-1 / fn 2-3): {ds_reads || 3 gload_lds ||
//    12-MFMA cluster} + mid-chunk barrier -> wave role diversity.
//  - s_setprio(1/0) around MFMA clusters (pays only with phase split).
//  - product-major MFMA order: same-acc dependent chain distance 1 -> 4.
// Kept from R10 (HW-validated): panelized workspace (1KB contiguous cells),
// 64x128 wave tiles of a 128x256 block tile, swizzle pair (read
// ^((l31>>2)&7)<<3 halfs / write via lane perm lp=lane^((lane>>3)&7),
// linear gload_lds dest), (256,2) launch bounds (NEVER (256,3): spill).
// SQ_LDS_BANK_CONFLICT = 8 x gload_lds count is a write-burst accounting
// artifact (invariant across R8->R9 layout change) — ignored.
// fp32 GEMM emulated as 3-term f16 (xh*wh + xh*wl + xl*wh), inputs
// pre-scaled 2^6, un-scaled 2^-12 at epilogue.

#define B_   256
#define T_   100
#define I_   512
#define H_   1024
#define C_   8
#define M_   (B_ * T_)        // 25600
#define SC   64.0f            // 2^6 pre-scale
#define ISC  (1.0f / 4096.0f) // 2^-12 epilogue un-scale

// Panel layout (halfs): cell = 32 rows x 16 halfs = 512 (1024 B contiguous);
// s-half = 32 chunks x cell = 16384; panel = hi|lo = 32768 (64 KB).
#define CELL_  512
#define SHALF_ 16384
#define PANEL_ 32768

typedef _Float16 half8 __attribute__((ext_vector_type(8)));
typedef float floatx16 __attribute__((ext_vector_type(16)));

__device__ __forceinline__ void ld_g2l(const _Float16* g, _Float16* l) {
    // async global->LDS, 16B/lane; LDS dest = wave-uniform base + lane*16
    __builtin_amdgcn_global_load_lds(
        (const __attribute__((address_space(1))) void*)g,
        (__attribute__((address_space(3))) void*)l, 16, 0, 0);
}

// Splitter: block p < 800 handles A panel p (x rows p*32+[0,32)); blocks
// 800..831 handle W1 panel p-800. 8 iters: wave w reads row j*4+w in full
// (64 lanes x 32B = 2KB, coalesced), splits, writes hi/lo 16B pieces into
// the row's slots of all 32 cells. Blocks 0..7 init logits.
__global__ void __launch_bounds__(256)
split_all(const float* __restrict__ x, const float* __restrict__ W1,
          const float* __restrict__ b2, _Float16* __restrict__ Asp,
          float* __restrict__ out) {
    const int tid = threadIdx.x;
    const int lane = tid & 63;
    const int w = tid >> 6;
    const int p = blockIdx.x;
    int g = p * 256 + tid;
    if (g < B_ * C_) out[g] = 100.0f * b2[g & (C_ - 1)];

    const bool isA = (p < 800);
    const int pl = isA ? p : (p - 800);
    const float* srcm = isA ? x : W1;
    _Float16* dstp = Asp + (size_t)(isA ? pl : (800 + pl)) * PANEL_;
#pragma unroll 2
    for (int j = 0; j < 8; ++j) {
        const int rl = j * 4 + w;                 // row 0..31 within panel
        const int r  = pl * 32 + rl;              // source matrix row
        const float* src = srcm + (size_t)r * I_ + lane * 8;
        float4 v0 = *(const float4*)(src);
        float4 v1 = *(const float4*)(src + 4);
        float vv[8] = {v0.x, v0.y, v0.z, v0.w, v1.x, v1.y, v1.z, v1.w};
        half8 hi, lo;
#pragma unroll
        for (int q = 0; q < 8; ++q) {
            float s = vv[q] * SC;
            _Float16 h = (_Float16)s;
            hi[q] = h;
            lo[q] = (_Float16)(s - (float)h);
        }
        // dest: cell = lane>>1 (=col/16), within-cell ofs rl*16 + (lane&1)*8
        _Float16* d = dstp + (lane >> 1) * CELL_ + rl * 16 + (lane & 1) * 8;
        *(half8*)(d) = hi;
        *(half8*)(d + SHALF_) = lo;
    }
}

#define MFMA32(A, Bv, Cacc) \
    Cacc = __builtin_amdgcn_mfma_f32_32x32x16_f16(A, Bv, Cacc, 0, 0, 0)

// Fused: C-tile[t 0..127][256 h], LIF scan + FC2. One batch per block, 4
// h-tiles of 256. XCD-swizzled: xcd=blk&7 owns batches [32*xcd, 32*xcd+32).
// A rows 100..127 overread into following panels (masked in scan).
// LDS buffer (halfs): Ah[128*16]=2048 @0 | Al @2048 | Bh[256*16]=4096 @4096
// | Bl @8192; buffer stride 12288 halfs (24 KB), 3 buffers.
__global__ void __launch_bounds__(256, 2)
snn_mfma(const _Float16* __restrict__ Asp, const _Float16* __restrict__ Wsp,
         const float* __restrict__ b1, const float* __restrict__ W2,
         float* __restrict__ logits) {
    __shared__ union {
        __align__(16) _Float16 buf[3][12288];  // 3-buffer pipeline (72 KB)
        float Cs[32 * 256];                    // epilogue staging (32 KB)
    } sm;
    const int tid = threadIdx.x;
    const int lane = tid & 63;
    const int w = tid >> 6;

    const int xcd = blockIdx.x & 7;
    const int jj = blockIdx.x >> 3;        // 0..127 per-XCD sequence
    const int b  = xcd * 32 + (jj >> 2);   // batch 0..255
    const int n0 = (jj & 3) * 256;         // h tile offset

    const int wm = (w >> 1) * 64;   // wave's 64x128 sub-tile
    const int wn = (w & 1) * 128;
    const int l31 = lane & 31;
    const int q2 = lane >> 5;

    // ---- staging pointers (write side of the swizzle) ----
    // lane l's gload_lds writes LDS halfs [base + l*8); it carries logical
    // lane lp = l ^ ((l>>3)&7) (involution): row lp>>1, 8-half group lp&1.
    const int lp = lane ^ ((lane >> 3) & 7);
    const int ra_row = b * T_ + w * 32 + (lp >> 1);        // A matrix row
    const int rb_row = n0 + w * 64 + (lp >> 1);            // B cell0 row
    const _Float16* gah = Asp + (size_t)(ra_row >> 5) * PANEL_
                              + (ra_row & 31) * 16 + (lp & 1) * 8;
    const _Float16* gal = gah + SHALF_;
    const _Float16* gbh0 = Wsp + (size_t)(rb_row >> 5) * PANEL_
                               + (rb_row & 31) * 16 + (lp & 1) * 8;
    const _Float16* gbh1 = gbh0 + PANEL_;      // +32 rows = next panel
    const _Float16* gbl0 = gbh0 + SHALF_;
    const _Float16* gbl1 = gbh1 + SHALF_;

    // ---- fragment LDS offsets (read side of the swizzle), half units ----
    // raw = row*16 + q2*8; XOR half-bits 3..5 with row bits 2..4. All added
    // offsets (f*512, region bases, buf*12288) are multiples of 512 halfs ->
    // commute with the XOR.
    const int swz = ((l31 >> 2) & 7) << 3;
    const int ra = ((wm + l31) * 16 + q2 * 8) ^ swz;
    const int rb = ((wn + l31) * 16 + q2 * 8) ^ swz;

    floatx16 acc[2][4];
#pragma unroll
    for (int i = 0; i < 2; ++i)
#pragma unroll
        for (int j = 0; j < 4; ++j)
#pragma unroll
            for (int e = 0; e < 16; ++e) acc[i][j][e] = 0.f;

    // ---- prologue: fully stage chunks 0 (buf0) and 1 (buf1) ----
#pragma unroll
    for (int c0 = 0; c0 < 2; ++c0) {
        _Float16* nb = &sm.buf[0][0] + c0 * 12288;
        ld_g2l(gah  + c0 * CELL_, nb + w * 512);
        ld_g2l(gal  + c0 * CELL_, nb + 2048 + w * 512);
        ld_g2l(gbh0 + c0 * CELL_, nb + 4096 + w * 1024);
        ld_g2l(gbh1 + c0 * CELL_, nb + 4096 + w * 1024 + 512);
        ld_g2l(gbl0 + c0 * CELL_, nb + 8192 + w * 1024);
        ld_g2l(gbl1 + c0 * CELL_, nb + 8192 + w * 1024 + 512);
    }
    asm volatile("s_waitcnt vmcnt(6)" ::: "memory");   // chunk 0 landed
    __builtin_amdgcn_s_barrier();

    int bufc = 0, bufn = 2;
    for (int c = 0; c < 32; ++c) {
        const _Float16* bb = &sm.buf[0][0] + bufc * 12288;
        _Float16* nb = &sm.buf[0][0] + bufn * 12288;
        half8 ah[2], al[2], bh[2], bl[2];
        // ======== phase A: fn 0,1 ========
        ah[0] = *(const half8*)(bb + ra);
        ah[1] = *(const half8*)(bb + ra + 512);
        al[0] = *(const half8*)(bb + 2048 + ra);
        al[1] = *(const half8*)(bb + 2048 + ra + 512);
        bh[0] = *(const half8*)(bb + 4096 + rb);
        bh[1] = *(const half8*)(bb + 4096 + rb + 512);
        bl[0] = *(const half8*)(bb + 8192 + rb);
        bl[1] = *(const half8*)(bb + 8192 + rb + 512);
        if (c < 30) {   // stage chunk c+2, first half
            const int cc = c + 2;
            ld_g2l(gah  + cc * CELL_, nb + w * 512);
            ld_g2l(gal  + cc * CELL_, nb + 2048 + w * 512);
            ld_g2l(gbh0 + cc * CELL_, nb + 4096 + w * 1024);
        }
        __builtin_amdgcn_s_setprio(1);
        MFMA32(ah[0], bh[0], acc[0][0]); MFMA32(ah[0], bh[1], acc[0][1]);
        MFMA32(ah[1], bh[0], acc[1][0]); MFMA32(ah[1], bh[1], acc[1][1]);
        MFMA32(ah[0], bl[0], acc[0][0]); MFMA32(ah[0], bl[1], acc[0][1]);
        MFMA32(ah[1], bl[0], acc[1][0]); MFMA32(ah[1], bl[1], acc[1][1]);
        MFMA32(al[0], bh[0], acc[0][0]); MFMA32(al[0], bh[1], acc[0][1]);
        MFMA32(al[1], bh[0], acc[1][0]); MFMA32(al[1], bh[1], acc[1][1]);
        __builtin_amdgcn_s_setprio(0);
        __builtin_amdgcn_s_barrier();   // mid-chunk phase barrier
        // ======== phase B: fn 2,3 ========
        bh[0] = *(const half8*)(bb + 4096 + rb + 1024);
        bh[1] = *(const half8*)(bb + 4096 + rb + 1536);
        bl[0] = *(const half8*)(bb + 8192 + rb + 1024);
        bl[1] = *(const half8*)(bb + 8192 + rb + 1536);
        if (c < 30) {   // stage chunk c+2, second half
            const int cc = c + 2;
            ld_g2l(gbh1 + cc * CELL_, nb + 4096 + w * 1024 + 512);
            ld_g2l(gbl0 + cc * CELL_, nb + 8192 + w * 1024);
            ld_g2l(gbl1 + cc * CELL_, nb + 8192 + w * 1024 + 512);
        }
        __builtin_amdgcn_s_setprio(1);
        MFMA32(ah[0], bh[0], acc[0][2]); MFMA32(ah[0], bh[1], acc[0][3]);
        MFMA32(ah[1], bh[0], acc[1][2]); MFMA32(ah[1], bh[1], acc[1][3]);
        MFMA32(ah[0], bl[0], acc[0][2]); MFMA32(ah[0], bl[1], acc[0][3]);
        MFMA32(ah[1], bl[0], acc[1][2]); MFMA32(ah[1], bl[1], acc[1][3]);
        MFMA32(al[0], bh[0], acc[0][2]); MFMA32(al[0], bh[1], acc[0][3]);
        MFMA32(al[1], bh[0], acc[1][2]); MFMA32(al[1], bh[1], acc[1][3]);
        __builtin_amdgcn_s_setprio(0);
        // ---- chunk boundary: next chunk's buffer must be landed ----
        if (c < 30) {
            asm volatile("s_waitcnt vmcnt(6)" ::: "memory");
            __builtin_amdgcn_s_barrier();
        } else if (c == 30) {
            asm volatile("s_waitcnt vmcnt(0)" ::: "memory");
            __builtin_amdgcn_s_barrier();
        }
        bufc = (bufc == 2) ? 0 : bufc + 1;
        bufn = (bufn == 2) ? 0 : bufn + 1;
    }
    __syncthreads();   // full fence before Cs overwrite

    // ---- epilogue: acc -> LDS (four 32-row phases) -> LIF scan + FC2 ----
    float b1c[4];
#pragma unroll
    for (int fn = 0; fn < 4; ++fn) b1c[fn] = b1[n0 + wn + fn * 32 + l31];

    float mem = 0.f, ss = 0.f;

    // phase p covers tile rows [32p, 32p+32): written by waves 0,1 (wm=0)
    // for p<2 with fm=p, by waves 2,3 for p>=2 with fm=p-2.
#pragma unroll
    for (int p = 0; p < 4; ++p) {
        const int fm = p & 1;
        if ((w >> 1) == (p >> 1)) {
#pragma unroll
            for (int r = 0; r < 16; ++r) {
                const int row = (r & 3) + 8 * (r >> 2) + 4 * q2;  // 0..31
                float* dst = &sm.Cs[row * 256 + wn + l31];
#pragma unroll
                for (int fn = 0; fn < 4; ++fn)
                    dst[fn * 32] = acc[fm][fn][r] * ISC + b1c[fn];
            }
        }
        __syncthreads();
        const int nt = (p == 3) ? 4 : 32;   // t 96..99 only in last phase
#pragma unroll 8
        for (int t = 0; t < nt; ++t) {
            float cv = sm.Cs[t * 256 + tid];
            float reset = (mem > 1.0f) ? 1.0f : 0.0f;
            mem = 0.9f * mem + cv - reset;
            ss += (mem > 1.0f) ? 1.0f : 0.0f;
        }
        __syncthreads();
    }

    // ---- FC2: logits[b][c] += sum_h ss * W2[c][h] ----
#pragma unroll
    for (int cc = 0; cc < C_; ++cc) {
        float v = ss * W2[cc * H_ + n0 + tid];
#pragma unroll
        for (int off = 32; off; off >>= 1) v += __shfl_down(v, off, 64);
        if (lane == 0) atomicAdd(&logits[b * C_ + cc], v);
    }
}

extern "C" void kernel_launch(void* const* d_in, const int* in_sizes, int n_in,
                              void* d_out, int out_size, void* d_ws, size_t ws_size,
                              hipStream_t stream) {
    const float* x  = (const float*)d_in[0];
    const float* W1 = (const float*)d_in[1];
    const float* b1 = (const float*)d_in[2];
    const float* W2 = (const float*)d_in[3];
    const float* b2 = (const float*)d_in[4];
    float* out = (float*)d_out;

    // workspace: Asp = 800 panels (52.4 MB), Wsp = 32 panels (2 MB) directly
    // after (fused kernel's tail rows overread into Wsp panels by design).
    char* ws = (char*)d_ws;
    _Float16* Asp = (_Float16*)ws;
    _Float16* Wsp = Asp + (size_t)800 * PANEL_;

    hipLaunchKernelGGL(split_all, dim3(832), dim3(256), 0, stream,
                       x, W1, b2, Asp, out);
    hipLaunchKernelGGL(snn_mfma, dim3(B_ * 4), dim3(256), 0, stream,
                       Asp, Wsp, b1, W2, out);
}

// Round 9
// 197.339 us; speedup vs baseline: 1.0622x; 1.0355x over previous
//
#include <hip/hip_runtime.h>

// SNN direction decoder — fused split+MFMA GEMM + LIF scan + FC2.
// B=256, T=100, I=512, H=1024, C=8.
// R12: kill split_all's A-side (~100us of non-snn time exists; split's
// 108MB traffic is the only controllable part). x's fp32->hi/lo f16 split
// now happens INSIDE snn_mfma staging:
//  - A: reg-staged. Per chunk, wave loads its 32row x 64B fp32 x-slice
//    (1 cacheline/row, L3-resident), converts (~40 VALU), ds_write_b128
//    directly to the swizzled LDS layout (linear^XOR; no source perm).
//  - B: unchanged gload_lds from pre-split panelized Wsp (2MB, W1-only
//    splitter = 32 blocks).
//  - vmcnt ledger (mixed gload_lds + global_load, 6 VMEM/chunk/wave in
//    chunk order): one vmcnt(6) per boundary covers A(c+1)-for-convert
//    and B(c+1)-for-read; A regs ping-pong 2 sets (unroll-2 static idx);
//    lgkmcnt(0)+sched_barrier(0) before the boundary barrier.
// Keeps R11's best-measured schedule: 3-buf depth-2 pipeline, 2 phases/
// chunk + mid barrier, setprio around MFMA clusters, 64x128 wave tiles of
// 128x256 block tile, 32x32x16 f16 MFMA, (256,2) bounds (NEVER (256,3)).
// fp32 GEMM = 3-term f16 (xh*wh + xh*wl + xl*wh), pre-scale 2^6,
// un-scale 2^-12 at epilogue. Scan masks t>=100 (pad rows garbage; x
// overread for b=255 clamped to row M_-1).

#define B_   256
#define T_   100
#define I_   512
#define H_   1024
#define C_   8
#define M_   (B_ * T_)        // 25600
#define SC   64.0f            // 2^6 pre-scale
#define ISC  (1.0f / 4096.0f) // 2^-12 epilogue un-scale

// Wsp panel layout (halfs): cell = 32 rows x 16 halfs = 512 (1024 B
// contiguous); s-half = 32 chunks x cell = 16384; panel = hi|lo = 32768.
#define CELL_  512
#define SHALF_ 16384
#define PANEL_ 32768

typedef _Float16 half8 __attribute__((ext_vector_type(8)));
typedef float floatx16 __attribute__((ext_vector_type(16)));

__device__ __forceinline__ void ld_g2l(const _Float16* g, _Float16* l) {
    // async global->LDS, 16B/lane; LDS dest = wave-uniform base + lane*16
    __builtin_amdgcn_global_load_lds(
        (const __attribute__((address_space(1))) void*)g,
        (__attribute__((address_space(3))) void*)l, 16, 0, 0);
}

__device__ __forceinline__ void cvt_split(const float4 v0, const float4 v1,
                                          half8& hi, half8& lo) {
    float vv[8] = {v0.x, v0.y, v0.z, v0.w, v1.x, v1.y, v1.z, v1.w};
#pragma unroll
    for (int q = 0; q < 8; ++q) {
        float s = vv[q] * SC;
        _Float16 h = (_Float16)s;
        hi[q] = h;
        lo[q] = (_Float16)(s - (float)h);
    }
}

// W1-only splitter: block p = W1 panel p (rows p*32+[0,32)). Wave w reads
// row j*4+w in full (2KB coalesced), writes hi/lo 16B pieces into the
// row's slots of all 32 cells. Blocks 0..7 also init logits.
__global__ void __launch_bounds__(256)
split_w1(const float* __restrict__ W1, const float* __restrict__ b2,
         _Float16* __restrict__ Wsp, float* __restrict__ out) {
    const int tid = threadIdx.x;
    const int lane = tid & 63;
    const int w = tid >> 6;
    const int p = blockIdx.x;
    int g = p * 256 + tid;
    if (g < B_ * C_) out[g] = 100.0f * b2[g & (C_ - 1)];

    _Float16* dstp = Wsp + (size_t)p * PANEL_;
#pragma unroll 2
    for (int j = 0; j < 8; ++j) {
        const int rl = j * 4 + w;                 // row 0..31 within panel
        const float* src = W1 + (size_t)(p * 32 + rl) * I_ + lane * 8;
        float4 v0 = *(const float4*)(src);
        float4 v1 = *(const float4*)(src + 4);
        half8 hi, lo;
        cvt_split(v0, v1, hi, lo);
        _Float16* d = dstp + (lane >> 1) * CELL_ + rl * 16 + (lane & 1) * 8;
        *(half8*)(d) = hi;
        *(half8*)(d + SHALF_) = lo;
    }
}

#define MFMA32(A, Bv, Cacc) \
    Cacc = __builtin_amdgcn_mfma_f32_32x32x16_f16(A, Bv, Cacc, 0, 0, 0)

// Fused: C-tile[t 0..127][256 h], LIF scan + FC2. One batch per block, 4
// h-tiles of 256. XCD-swizzled: xcd=blk&7 owns batches [32*xcd, 32*xcd+32).
// LDS buffer (halfs): Ah[128*16] @0 | Al @2048 | Bh[256*16] @4096 | Bl
// @8192; stride 12288 (24 KB), 3 buffers.
__global__ void __launch_bounds__(256, 2)
snn_mfma(const float* __restrict__ x, const _Float16* __restrict__ Wsp,
         const float* __restrict__ b1, const float* __restrict__ W2,
         float* __restrict__ logits) {
    __shared__ union {
        __align__(16) _Float16 buf[3][12288];  // 3-buffer pipeline (72 KB)
        float Cs[32 * 256];                    // epilogue staging (32 KB)
    } sm;
    const int tid = threadIdx.x;
    const int lane = tid & 63;
    const int w = tid >> 6;

    const int xcd = blockIdx.x & 7;
    const int jj = blockIdx.x >> 3;        // 0..127 per-XCD sequence
    const int b  = xcd * 32 + (jj >> 2);   // batch 0..255
    const int n0 = (jj & 3) * 256;         // h tile offset

    const int wm = (w >> 1) * 64;   // wave's 64x128 sub-tile
    const int wn = (w & 1) * 128;
    const int l31 = lane & 31;
    const int q2 = lane >> 5;

    // ---- B staging pointers (write side of swizzle via lane perm) ----
    const int lp = lane ^ ((lane >> 3) & 7);
    const int rb_row = n0 + w * 64 + (lp >> 1);            // B cell0 row
    const _Float16* gbh0 = Wsp + (size_t)(rb_row >> 5) * PANEL_
                               + (rb_row & 31) * 16 + (lp & 1) * 8;
    const _Float16* gbh1 = gbh0 + PANEL_;      // +32 rows = next panel
    const _Float16* gbl0 = gbh0 + SHALF_;
    const _Float16* gbl1 = gbh1 + SHALF_;

    // ---- A: per-lane x pointer (reg-staged) + swizzled ds_write ofs ----
    int rowm = b * T_ + w * 32 + (lane >> 1);   // rows 100..127 overread
    if (rowm > M_ - 1) rowm = M_ - 1;           // clamp (b=255 tail)
    const float* gxa = x + (size_t)rowm * I_ + (lane & 1) * 8;
    // write addr (halfs): raw lane*8, XOR key = row bits 2..4 = (lane>>3)&7
    const int wofs = (lane * 8) ^ (((lane >> 3) & 7) << 3) + 0;
    _Float16* const abase = &sm.buf[0][0] + w * 512;  // wave's A row window

    // ---- fragment read offsets (swizzled), half units ----
    const int swz = ((l31 >> 2) & 7) << 3;
    const int ra = ((wm + l31) * 16 + q2 * 8) ^ swz;
    const int rb = ((wn + l31) * 16 + q2 * 8) ^ swz;

    floatx16 acc[2][4];
#pragma unroll
    for (int i = 0; i < 2; ++i)
#pragma unroll
        for (int j = 0; j < 4; ++j)
#pragma unroll
            for (int e = 0; e < 16; ++e) acc[i][j][e] = 0.f;

    float4 rxa0, rxb0, rxa1, rxb1;   // A reg sets (8 fp32 each)

    // ---- prologue: chunks 0,1 — order per chunk: [Bh x2, A x2, Bl x2] ----
    {
        _Float16* nb0 = &sm.buf[0][0];
        _Float16* nb1 = &sm.buf[0][0] + 12288;
        ld_g2l(gbh0, nb0 + 4096 + w * 1024);
        ld_g2l(gbh1, nb0 + 4096 + w * 1024 + 512);
        rxa0 = *(const float4*)(gxa);
        rxb0 = *(const float4*)(gxa + 4);
        ld_g2l(gbl0, nb0 + 8192 + w * 1024);
        ld_g2l(gbl1, nb0 + 8192 + w * 1024 + 512);
        ld_g2l(gbh0 + CELL_, nb1 + 4096 + w * 1024);
        ld_g2l(gbh1 + CELL_, nb1 + 4096 + w * 1024 + 512);
        rxa1 = *(const float4*)(gxa + 16);
        rxb1 = *(const float4*)(gxa + 20);
        ld_g2l(gbl0 + CELL_, nb1 + 8192 + w * 1024);
        ld_g2l(gbl1 + CELL_, nb1 + 8192 + w * 1024 + 512);
        // A(0)+B(0) landed when only chunk-1's 6 ops may remain:
        asm volatile("s_waitcnt vmcnt(6)" ::: "memory");
        half8 hi, lo;
        cvt_split(rxa0, rxb0, hi, lo);
        *(half8*)(abase + wofs) = hi;           // Ah @0
        *(half8*)(abase + 2048 + wofs) = lo;    // Al @2048
        asm volatile("s_waitcnt lgkmcnt(0)" ::: "memory");
        __builtin_amdgcn_sched_barrier(0);
        __builtin_amdgcn_s_barrier();
        asm volatile("" ::: "memory");
    }

    int bufc = 0;
#pragma unroll 2
    for (int c = 0; c < 32; ++c) {
        const int bufn1 = (bufc == 2) ? 0 : bufc + 1;   // (c+1)%3
        const int bufn2 = (bufn1 == 2) ? 0 : bufn1 + 1; // (c+2)%3
        const _Float16* bb = &sm.buf[0][0] + bufc * 12288;
        _Float16* nb = &sm.buf[0][0] + bufn2 * 12288;
        half8 ah[2], al[2], bh[2], bl[2];
        // ======== phase A: fn 0,1 ========
        ah[0] = *(const half8*)(bb + ra);
        ah[1] = *(const half8*)(bb + ra + 512);
        al[0] = *(const half8*)(bb + 2048 + ra);
        al[1] = *(const half8*)(bb + 2048 + ra + 512);
        bh[0] = *(const half8*)(bb + 4096 + rb);
        bh[1] = *(const half8*)(bb + 4096 + rb + 512);
        bl[0] = *(const half8*)(bb + 8192 + rb);
        bl[1] = *(const half8*)(bb + 8192 + rb + 512);
        if (c < 30) {
            ld_g2l(gbh0 + (c + 2) * CELL_, nb + 4096 + w * 1024);
            ld_g2l(gbh1 + (c + 2) * CELL_, nb + 4096 + w * 1024 + 512);
            if ((c & 1) == 0) {      // load A(c+2) into set0
                rxa0 = *(const float4*)(gxa + (c + 2) * 16);
                rxb0 = *(const float4*)(gxa + (c + 2) * 16 + 4);
            } else {                 // into set1
                rxa1 = *(const float4*)(gxa + (c + 2) * 16);
                rxb1 = *(const float4*)(gxa + (c + 2) * 16 + 4);
            }
        }
        __builtin_amdgcn_s_setprio(1);
        MFMA32(ah[0], bh[0], acc[0][0]); MFMA32(ah[0], bh[1], acc[0][1]);
        MFMA32(ah[1], bh[0], acc[1][0]); MFMA32(ah[1], bh[1], acc[1][1]);
        MFMA32(ah[0], bl[0], acc[0][0]); MFMA32(ah[0], bl[1], acc[0][1]);
        MFMA32(ah[1], bl[0], acc[1][0]); MFMA32(ah[1], bl[1], acc[1][1]);
        MFMA32(al[0], bh[0], acc[0][0]); MFMA32(al[0], bh[1], acc[0][1]);
        MFMA32(al[1], bh[0], acc[1][0]); MFMA32(al[1], bh[1], acc[1][1]);
        __builtin_amdgcn_s_setprio(0);
        __builtin_amdgcn_s_barrier();   // mid-chunk phase barrier
        asm volatile("" ::: "memory");
        // ======== phase B: fn 2,3 ========
        bh[0] = *(const half8*)(bb + 4096 + rb + 1024);
        bh[1] = *(const half8*)(bb + 4096 + rb + 1536);
        bl[0] = *(const half8*)(bb + 8192 + rb + 1024);
        bl[1] = *(const half8*)(bb + 8192 + rb + 1536);
        if (c < 30) {
            ld_g2l(gbl0 + (c + 2) * CELL_, nb + 8192 + w * 1024);
            ld_g2l(gbl1 + (c + 2) * CELL_, nb + 8192 + w * 1024 + 512);
        }
        __builtin_amdgcn_s_setprio(1);
        MFMA32(ah[0], bh[0], acc[0][2]); MFMA32(ah[0], bh[1], acc[0][3]);
        MFMA32(ah[1], bh[0], acc[1][2]); MFMA32(ah[1], bh[1], acc[1][3]);
        MFMA32(ah[0], bl[0], acc[0][2]); MFMA32(ah[0], bl[1], acc[0][3]);
        MFMA32(ah[1], bl[0], acc[1][2]); MFMA32(ah[1], bl[1], acc[1][3]);
        MFMA32(al[0], bh[0], acc[0][2]); MFMA32(al[0], bh[1], acc[0][3]);
        MFMA32(al[1], bh[0], acc[1][2]); MFMA32(al[1], bh[1], acc[1][3]);
        __builtin_amdgcn_s_setprio(0);
        // ---- chunk boundary ----
        if (c < 30) {
            // A(c+1),B(c+1) landed when only chunk-c's 6 ops may remain
            asm volatile("s_waitcnt vmcnt(6)" ::: "memory");
        } else if (c == 30) {
            asm volatile("s_waitcnt vmcnt(0)" ::: "memory");
        }
        if (c < 31) {   // convert+write A(c+1) -> buf (c+1)%3
            half8 hi, lo;
            if ((c & 1) == 0) cvt_split(rxa1, rxb1, hi, lo);  // A(c+1) in set1
            else              cvt_split(rxa0, rxb0, hi, lo);  // in set0
            _Float16* ab = &sm.buf[0][0] + bufn1 * 12288 + w * 512;
            *(half8*)(ab + wofs) = hi;
            *(half8*)(ab + 2048 + wofs) = lo;
            asm volatile("s_waitcnt lgkmcnt(0)" ::: "memory");
            __builtin_amdgcn_sched_barrier(0);
        }
        __builtin_amdgcn_s_barrier();
        asm volatile("" ::: "memory");
        bufc = bufn1;
    }
    __syncthreads();   // full fence before Cs overwrite

    // ---- epilogue: acc -> LDS (four 32-row phases) -> LIF scan + FC2 ----
    float b1c[4];
#pragma unroll
    for (int fn = 0; fn < 4; ++fn) b1c[fn] = b1[n0 + wn + fn * 32 + l31];

    float mem = 0.f, ss = 0.f;

#pragma unroll
    for (int p = 0; p < 4; ++p) {
        const int fm = p & 1;
        if ((w >> 1) == (p >> 1)) {
#pragma unroll
            for (int r = 0; r < 16; ++r) {
                const int row = (r & 3) + 8 * (r >> 2) + 4 * q2;  // 0..31
                float* dst = &sm.Cs[row * 256 + wn + l31];
#pragma unroll
                for (int fn = 0; fn < 4; ++fn)
                    dst[fn * 32] = acc[fm][fn][r] * ISC + b1c[fn];
            }
        }
        __syncthreads();
        const int nt = (p == 3) ? 4 : 32;   // t 96..99 only in last phase
#pragma unroll 8
        for (int t = 0; t < nt; ++t) {
            float cv = sm.Cs[t * 256 + tid];
            float reset = (mem > 1.0f) ? 1.0f : 0.0f;
            mem = 0.9f * mem + cv - reset;
            ss += (mem > 1.0f) ? 1.0f : 0.0f;
        }
        __syncthreads();
    }

    // ---- FC2: logits[b][c] += sum_h ss * W2[c][h] ----
#pragma unroll
    for (int cc = 0; cc < C_; ++cc) {
        float v = ss * W2[cc * H_ + n0 + tid];
#pragma unroll
        for (int off = 32; off; off >>= 1) v += __shfl_down(v, off, 64);
        if (lane == 0) atomicAdd(&logits[b * C_ + cc], v);
    }
}

extern "C" void kernel_launch(void* const* d_in, const int* in_sizes, int n_in,
                              void* d_out, int out_size, void* d_ws, size_t ws_size,
                              hipStream_t stream) {
    const float* x  = (const float*)d_in[0];
    const float* W1 = (const float*)d_in[1];
    const float* b1 = (const float*)d_in[2];
    const float* W2 = (const float*)d_in[3];
    const float* b2 = (const float*)d_in[4];
    float* out = (float*)d_out;

    // workspace: Wsp = 32 panels (2 MB) only — Asp eliminated.
    _Float16* Wsp = (_Float16*)d_ws;

    hipLaunchKernelGGL(split_w1, dim3(32), dim3(256), 0, stream,
                       W1, b2, Wsp, out);
    hipLaunchKernelGGL(snn_mfma, dim3(B_ * 4), dim3(256), 0, stream,
                       x, Wsp, b1, W2, out);
}